// Round 1
// baseline (350.388 us; speedup 1.0000x reference)
//
#include <hip/hip_runtime.h>
#include <stdint.h>

#define B_ 4
#define L_ 2048
#define D_ 1024
#define H_ 16
#define DK_ 64

typedef __attribute__((ext_vector_type(8))) short bf16x8;
typedef __attribute__((ext_vector_type(4))) float f32x4;
typedef unsigned short bfu;   // raw bf16 storage

#define MFMA(a, b, c) __builtin_amdgcn_mfma_f32_16x16x32_bf16((a), (b), (c), 0, 0, 0)

__device__ __forceinline__ unsigned short f2bf(float f) {
  union { float f; unsigned int u; } v; v.f = f;
  unsigned int u = v.u;
  return (unsigned short)((u + 0x7fffu + ((u >> 16) & 1u)) >> 16);  // RNE
}

__device__ __forceinline__ void gll16(const void* g, void* l) {
  __builtin_amdgcn_global_load_lds(
      (const __attribute__((address_space(1))) void*)g,
      (__attribute__((address_space(3))) void*)l, 16, 0, 0);
}

// ---------------- prep kernels ----------------

__global__ __launch_bounds__(256) void cast_x(const float* __restrict__ in,
                                              bfu* __restrict__ out, int n4) {
  int i = blockIdx.x * 256 + threadIdx.x;
  if (i >= n4) return;
  float4 v = ((const float4*)in)[i];
  ushort4 o;
  o.x = f2bf(v.x); o.y = f2bf(v.y); o.z = f2bf(v.z); o.w = f2bf(v.w);
  ((ushort4*)out)[i] = o;
}

// in[R][C] fp32 -> out[C][R] bf16
__global__ void transpose_cast(const float* __restrict__ in, bfu* __restrict__ out,
                               int R, int C) {
  __shared__ float tile[32][33];
  int c0 = blockIdx.x * 32, r0 = blockIdx.y * 32;
  int tx = threadIdx.x, ty = threadIdx.y;  // 32 x 8
#pragma unroll
  for (int i = ty; i < 32; i += 8)
    tile[i][tx] = in[(size_t)(r0 + i) * C + c0 + tx];
  __syncthreads();
#pragma unroll
  for (int i = ty; i < 32; i += 8)
    out[(size_t)(c0 + i) * R + r0 + tx] = f2bf(tile[tx][i]);
}

// ---------------- BT GEMM: C[M][N] = A[M][K] * Bt[N][K]^T ----------------
// EPI 0: scatter to Q (scaled 1/8), K ([B,H,L,DK]) and Vt ([B,H,DK,L]), bf16
// EPI 1: fp32 out[M][N] += bias

template <int EPI>
__global__ __launch_bounds__(256, 2) void gemm_bt(
    const bfu* __restrict__ A, const bfu* __restrict__ Bt,
    const float* __restrict__ bias, bfu* __restrict__ Qg, bfu* __restrict__ Kg,
    bfu* __restrict__ Vtg, float* __restrict__ Out, int M, int N, int K) {
  __shared__ __align__(16) bfu As[128 * 64];
  __shared__ __align__(16) bfu Bs[128 * 64];
  const int tid = threadIdx.x;
  const int lane = tid & 63;
  const int w = tid >> 6;
  const int wr = w >> 1, wc = w & 1;
  const int m0 = blockIdx.y * 128;
  const int n0 = blockIdx.x * 128;
  const int l15 = lane & 15, l4 = lane >> 4;

  f32x4 acc[4][4] = {};

  for (int k0 = 0; k0 < K; k0 += 64) {
    __syncthreads();
#pragma unroll
    for (int i = 0; i < 4; ++i) {
      int lb = i * 256 + tid;
      int r = lb >> 3;           // row in tile
      int c16p = lb & 7;         // physical 16B block in row
      int c16 = c16p ^ (r & 7);  // logical 16B block (pre-swizzled source)
      gll16(A + (size_t)(m0 + r) * K + k0 + c16 * 8, (char*)As + (size_t)lb * 16);
      gll16(Bt + (size_t)(n0 + r) * K + k0 + c16 * 8, (char*)Bs + (size_t)lb * 16);
    }
    __syncthreads();
#pragma unroll
    for (int kk = 0; kk < 2; ++kk) {
      bf16x8 af[4], bfr[4];
#pragma unroll
      for (int mi = 0; mi < 4; ++mi) {
        int r = wr * 64 + mi * 16 + l15;
        int c16 = (kk * 4 + l4) ^ (r & 7);
        af[mi] = *(const bf16x8*)((const char*)As + (size_t)r * 128 + c16 * 16);
      }
#pragma unroll
      for (int ni = 0; ni < 4; ++ni) {
        int r = wc * 64 + ni * 16 + l15;
        int c16 = (kk * 4 + l4) ^ (r & 7);
        bfr[ni] = *(const bf16x8*)((const char*)Bs + (size_t)r * 128 + c16 * 16);
      }
#pragma unroll
      for (int mi = 0; mi < 4; ++mi)
#pragma unroll
        for (int ni = 0; ni < 4; ++ni)
          acc[mi][ni] = MFMA(af[mi], bfr[ni], acc[mi][ni]);
    }
  }

  // epilogue: C/D layout col = lane&15, row = (lane>>4)*4 + reg
#pragma unroll
  for (int ni = 0; ni < 4; ++ni) {
    int gn = n0 + wc * 64 + ni * 16 + l15;
    float bv = bias[gn];
    if (EPI == 0) {
      int sec = gn >> 10;
      int rem = gn & 1023;
      int hh = rem >> 6, dk = rem & 63;
#pragma unroll
      for (int mi = 0; mi < 4; ++mi) {
#pragma unroll
        for (int rg = 0; rg < 4; ++rg) {
          int gm = m0 + wr * 64 + mi * 16 + l4 * 4 + rg;
          int bb = gm >> 11, ll = gm & 2047;
          float v = acc[mi][ni][rg] + bv;
          size_t hd = (size_t)(bb * H_ + hh);
          if (sec == 0)
            Qg[(hd * L_ + ll) * DK_ + dk] = f2bf(v * 0.125f);
          else if (sec == 1)
            Kg[(hd * L_ + ll) * DK_ + dk] = f2bf(v);
          else
            Vtg[(hd * DK_ + dk) * L_ + ll] = f2bf(v);
        }
      }
    } else {
#pragma unroll
      for (int mi = 0; mi < 4; ++mi)
#pragma unroll
        for (int rg = 0; rg < 4; ++rg) {
          int gm = m0 + wr * 64 + mi * 16 + l4 * 4 + rg;
          Out[(size_t)gm * 1024 + gn] = acc[mi][ni][rg] + bv;
        }
    }
  }
}

// ---------------- flash attention (causal) ----------------
// grid: (L/64, B*H); block 256 = 4 waves; wave w owns q rows [q0+16w, q0+16w+16)

__global__ __launch_bounds__(256) void attn(const bfu* __restrict__ Qg,
                                            const bfu* __restrict__ Kg,
                                            const bfu* __restrict__ Vtg,
                                            bfu* __restrict__ Ao) {
  __shared__ __align__(16) bfu Qs[64 * 64];
  __shared__ __align__(16) bfu Ks[64 * 64];
  __shared__ __align__(16) bfu Vs[64 * 64];
  __shared__ __align__(16) bfu Ps[64][72];  // padded: stride 144B

  const int tid = threadIdx.x;
  const int lane = tid & 63;
  const int w = tid >> 6;
  const int l15 = lane & 15, l4 = lane >> 4;
  const int bh = blockIdx.y;
  const int q0 = blockIdx.x * 64;
  const int b = bh >> 4, h = bh & 15;

  // stage Q tile (swizzled source, linear LDS)
#pragma unroll
  for (int i = 0; i < 2; ++i) {
    int lb = i * 256 + tid;
    int r = lb >> 3, c16p = lb & 7, c16 = c16p ^ (r & 7);
    gll16(Qg + ((size_t)bh * L_ + q0 + r) * DK_ + c16 * 8, (char*)Qs + (size_t)lb * 16);
  }
  __syncthreads();

  bf16x8 qf[2];
#pragma unroll
  for (int kk = 0; kk < 2; ++kk) {
    int r = w * 16 + l15;
    int c16 = (kk * 4 + l4) ^ (r & 7);
    qf[kk] = *(const bf16x8*)((const char*)Qs + (size_t)r * 128 + c16 * 16);
  }

  f32x4 acco[4] = {};
  float mstate[4] = {-1e30f, -1e30f, -1e30f, -1e30f};
  float lstate[4] = {0.f, 0.f, 0.f, 0.f};

  const int ntiles = q0 / 64 + 1;
  for (int t = 0; t < ntiles; ++t) {
    const int kv0 = t * 64;
    __syncthreads();  // all waves done reading Ks/Vs from prev tile
#pragma unroll
    for (int i = 0; i < 2; ++i) {
      int lb = i * 256 + tid;
      int r = lb >> 3, c16p = lb & 7, c16 = c16p ^ (r & 7);
      gll16(Kg + ((size_t)bh * L_ + kv0 + r) * DK_ + c16 * 8, (char*)Ks + (size_t)lb * 16);
      gll16(Vtg + ((size_t)bh * DK_ + r) * L_ + kv0 + c16 * 8, (char*)Vs + (size_t)lb * 16);
    }
    __syncthreads();  // drains vmcnt: tiles ready

    // S = Q K^T  (16 q-rows x 64 kv per wave)
    f32x4 s[4] = {};
#pragma unroll
    for (int kk = 0; kk < 2; ++kk)
#pragma unroll
      for (int ni = 0; ni < 4; ++ni) {
        int r = ni * 16 + l15;
        int c16 = (kk * 4 + l4) ^ (r & 7);
        bf16x8 kf = *(const bf16x8*)((const char*)Ks + (size_t)r * 128 + c16 * 16);
        s[ni] = MFMA(qf[kk], kf, s[ni]);
      }

    if (t == ntiles - 1) {  // diagonal tile: mask kv > q
#pragma unroll
      for (int ni = 0; ni < 4; ++ni)
#pragma unroll
        for (int rg = 0; rg < 4; ++rg) {
          int qg_ = q0 + w * 16 + l4 * 4 + rg;
          int kvg = kv0 + ni * 16 + l15;
          if (kvg > qg_) s[ni][rg] = -1e30f;
        }
    }

    // online softmax (row = (l4)*4+rg, cols spread over ni and l15-group)
#pragma unroll
    for (int rg = 0; rg < 4; ++rg) {
      float mx = fmaxf(fmaxf(s[0][rg], s[1][rg]), fmaxf(s[2][rg], s[3][rg]));
      mx = fmaxf(mx, __shfl_xor(mx, 1));
      mx = fmaxf(mx, __shfl_xor(mx, 2));
      mx = fmaxf(mx, __shfl_xor(mx, 4));
      mx = fmaxf(mx, __shfl_xor(mx, 8));
      float mnew = fmaxf(mstate[rg], mx);
      float scale = __expf(mstate[rg] - mnew);
      float sum = 0.f;
#pragma unroll
      for (int ni = 0; ni < 4; ++ni) {
        float p = __expf(s[ni][rg] - mnew);
        s[ni][rg] = p;
        sum += p;
      }
      sum += __shfl_xor(sum, 1);
      sum += __shfl_xor(sum, 2);
      sum += __shfl_xor(sum, 4);
      sum += __shfl_xor(sum, 8);
      lstate[rg] = lstate[rg] * scale + sum;
      mstate[rg] = mnew;
#pragma unroll
      for (int ni = 0; ni < 4; ++ni) acco[ni][rg] *= scale;
    }

    // P -> LDS (own rows only; no cross-wave dependency)
#pragma unroll
    for (int ni = 0; ni < 4; ++ni)
#pragma unroll
      for (int rg = 0; rg < 4; ++rg)
        Ps[w * 16 + l4 * 4 + rg][ni * 16 + l15] = f2bf(s[ni][rg]);

    // O += P V   (A = P[q][kv] from Ps, B^T = Vs[d][kv])
#pragma unroll
    for (int kk = 0; kk < 2; ++kk) {
      bf16x8 pf = *(const bf16x8*)((const char*)&Ps[w * 16 + l15][kk * 32 + l4 * 8]);
#pragma unroll
      for (int ni = 0; ni < 4; ++ni) {
        int r = ni * 16 + l15;
        int c16 = (kk * 4 + l4) ^ (r & 7);
        bf16x8 vf = *(const bf16x8*)((const char*)Vs + (size_t)r * 128 + c16 * 16);
        acco[ni] = MFMA(pf, vf, acco[ni]);
      }
    }
  }

  // epilogue: Ao[b][l][h*64+d] bf16
#pragma unroll
  for (int ni = 0; ni < 4; ++ni) {
    int d = ni * 16 + l15;
#pragma unroll
    for (int rg = 0; rg < 4; ++rg) {
      int lq = q0 + w * 16 + l4 * 4 + rg;
      float v = acco[ni][rg] / lstate[rg];
      Ao[((size_t)b * L_ + lq) * D_ + h * DK_ + d] = f2bf(v);
    }
  }
}

// ---------------- launch ----------------

extern "C" void kernel_launch(void* const* d_in, const int* in_sizes, int n_in,
                              void* d_out, int out_size, void* d_ws, size_t ws_size,
                              hipStream_t stream) {
  const float* x = (const float*)d_in[0];
  const float* W_qkv = (const float*)d_in[1];
  const float* b_qkv = (const float*)d_in[2];
  const float* W_out = (const float*)d_in[3];
  const float* b_out = (const float*)d_in[4];
  float* out = (float*)d_out;

  char* ws = (char*)d_ws;
  bfu* xb     = (bfu*)(ws);                    // 8192*1024*2   = 16,777,216
  bfu* Wqkv_t = (bfu*)(ws + 16777216);         // 3072*1024*2   =  6,291,456
  bfu* Wout_t = (bfu*)(ws + 23068672);         // 1024*1024*2   =  2,097,152
  bfu* Qg     = (bfu*)(ws + 25165824);         // 16,777,216
  bfu* Kg     = (bfu*)(ws + 41943040);         // 16,777,216
  bfu* Vtg    = (bfu*)(ws + 58720256);         // 16,777,216
  bfu* Ao     = (bfu*)(ws + 75497472);         // 16,777,216  (total ~92.3 MB)

  cast_x<<<8192, 256, 0, stream>>>(x, xb, 2097152);
  transpose_cast<<<dim3(96, 32), dim3(32, 8), 0, stream>>>(W_qkv, Wqkv_t, 1024, 3072);
  transpose_cast<<<dim3(32, 32), dim3(32, 8), 0, stream>>>(W_out, Wout_t, 1024, 1024);

  gemm_bt<0><<<dim3(24, 64), 256, 0, stream>>>(xb, Wqkv_t, b_qkv, Qg, Kg, Vtg,
                                               nullptr, 8192, 3072, 1024);
  attn<<<dim3(32, 64), 256, 0, stream>>>(Qg, Kg, Vtg, Ao);
  gemm_bt<1><<<dim3(8, 64), 256, 0, stream>>>(Ao, Wout_t, b_out, nullptr, nullptr,
                                              nullptr, out, 8192, 1024, 1024);
}

// Round 2
// 253.121 us; speedup vs baseline: 1.3843x; 1.3843x over previous
//
#include <hip/hip_runtime.h>
#include <stdint.h>

#define B_ 4
#define L_ 2048
#define D_ 1024
#define H_ 16
#define DK_ 64

typedef __attribute__((ext_vector_type(8))) short bf16x8;
typedef __attribute__((ext_vector_type(4))) float f32x4;
typedef unsigned short bfu;   // raw bf16 storage

#define MFMA(a, b, c) __builtin_amdgcn_mfma_f32_16x16x32_bf16((a), (b), (c), 0, 0, 0)

__device__ __forceinline__ unsigned short f2bf(float f) {
  union { float f; unsigned int u; } v; v.f = f;
  unsigned int u = v.u;
  return (unsigned short)((u + 0x7fffu + ((u >> 16) & 1u)) >> 16);  // RNE
}

__device__ __forceinline__ void gll16(const void* g, void* l) {
  __builtin_amdgcn_global_load_lds(
      (const __attribute__((address_space(1))) void*)g,
      (__attribute__((address_space(3))) void*)l, 16, 0, 0);
}

// ---------------- prep kernels ----------------

__global__ __launch_bounds__(256) void cast_x(const float* __restrict__ in,
                                              bfu* __restrict__ out, int n4) {
  int i = blockIdx.x * 256 + threadIdx.x;
  if (i >= n4) return;
  float4 v = ((const float4*)in)[i];
  ushort4 o;
  o.x = f2bf(v.x); o.y = f2bf(v.y); o.z = f2bf(v.z); o.w = f2bf(v.w);
  ((ushort4*)out)[i] = o;
}

// in[R][C] fp32 -> out[C][R] bf16
__global__ void transpose_cast(const float* __restrict__ in, bfu* __restrict__ out,
                               int R, int C) {
  __shared__ float tile[32][33];
  int c0 = blockIdx.x * 32, r0 = blockIdx.y * 32;
  int tx = threadIdx.x, ty = threadIdx.y;  // 32 x 8
#pragma unroll
  for (int i = ty; i < 32; i += 8)
    tile[i][tx] = in[(size_t)(r0 + i) * C + c0 + tx];
  __syncthreads();
#pragma unroll
  for (int i = ty; i < 32; i += 8)
    out[(size_t)(c0 + i) * R + r0 + tx] = f2bf(tile[tx][i]);
}

// ---------------- BT GEMM: C[M][N] = A[M][K] * Bt[N][K]^T ----------------
// EPI 0: scatter to Q (scaled 1/8 * log2e), K ([B,H,L,DK]) and Vt ([B,H,DK,L])
// EPI 1: fp32 out[M][N] += bias

template <int EPI>
__global__ __launch_bounds__(256, 2) void gemm_bt(
    const bfu* __restrict__ A, const bfu* __restrict__ Bt,
    const float* __restrict__ bias, bfu* __restrict__ Qg, bfu* __restrict__ Kg,
    bfu* __restrict__ Vtg, float* __restrict__ Out, int M, int N, int K) {
  __shared__ __align__(16) bfu As[128 * 64];
  __shared__ __align__(16) bfu Bs[128 * 64];
  const int tid = threadIdx.x;
  const int lane = tid & 63;
  const int w = tid >> 6;
  const int wr = w >> 1, wc = w & 1;
  const int m0 = blockIdx.y * 128;
  const int n0 = blockIdx.x * 128;
  const int l15 = lane & 15, l4 = lane >> 4;

  f32x4 acc[4][4] = {};

  for (int k0 = 0; k0 < K; k0 += 64) {
    __syncthreads();
#pragma unroll
    for (int i = 0; i < 4; ++i) {
      int lb = i * 256 + tid;
      int r = lb >> 3;           // row in tile
      int c16p = lb & 7;         // physical 16B block in row
      int c16 = c16p ^ (r & 7);  // logical 16B block (pre-swizzled source)
      gll16(A + (size_t)(m0 + r) * K + k0 + c16 * 8, (char*)As + (size_t)lb * 16);
      gll16(Bt + (size_t)(n0 + r) * K + k0 + c16 * 8, (char*)Bs + (size_t)lb * 16);
    }
    __syncthreads();
#pragma unroll
    for (int kk = 0; kk < 2; ++kk) {
      bf16x8 af[4], bfr[4];
#pragma unroll
      for (int mi = 0; mi < 4; ++mi) {
        int r = wr * 64 + mi * 16 + l15;
        int c16 = (kk * 4 + l4) ^ (r & 7);
        af[mi] = *(const bf16x8*)((const char*)As + (size_t)r * 128 + c16 * 16);
      }
#pragma unroll
      for (int ni = 0; ni < 4; ++ni) {
        int r = wc * 64 + ni * 16 + l15;
        int c16 = (kk * 4 + l4) ^ (r & 7);
        bfr[ni] = *(const bf16x8*)((const char*)Bs + (size_t)r * 128 + c16 * 16);
      }
#pragma unroll
      for (int mi = 0; mi < 4; ++mi)
#pragma unroll
        for (int ni = 0; ni < 4; ++ni)
          acc[mi][ni] = MFMA(af[mi], bfr[ni], acc[mi][ni]);
    }
  }

  // epilogue: C/D layout col = lane&15, row = (lane>>4)*4 + reg
#pragma unroll
  for (int ni = 0; ni < 4; ++ni) {
    int gn = n0 + wc * 64 + ni * 16 + l15;
    float bv = bias[gn];
    if (EPI == 0) {
      int sec = gn >> 10;
      int rem = gn & 1023;
      int hh = rem >> 6, dk = rem & 63;
#pragma unroll
      for (int mi = 0; mi < 4; ++mi) {
#pragma unroll
        for (int rg = 0; rg < 4; ++rg) {
          int gm = m0 + wr * 64 + mi * 16 + l4 * 4 + rg;
          int bb = gm >> 11, ll = gm & 2047;
          float v = acc[mi][ni][rg] + bv;
          size_t hd = (size_t)(bb * H_ + hh);
          if (sec == 0)
            Qg[(hd * L_ + ll) * DK_ + dk] = f2bf(v * 0.18033688011112042f);  // (1/8)*log2(e)
          else if (sec == 1)
            Kg[(hd * L_ + ll) * DK_ + dk] = f2bf(v);
          else
            Vtg[(hd * DK_ + dk) * L_ + ll] = f2bf(v);
        }
      }
    } else {
#pragma unroll
      for (int mi = 0; mi < 4; ++mi)
#pragma unroll
        for (int rg = 0; rg < 4; ++rg) {
          int gm = m0 + wr * 64 + mi * 16 + l4 * 4 + rg;
          Out[(size_t)gm * 1024 + gn] = acc[mi][ni][rg] + bv;
        }
    }
  }
}

// ---------------- flash attention (causal), exp2 domain ----------------
// grid: (8, B*H); block 256 = 4 waves. Block p handles q-blocks {p, 15-p}
// (128 rows each) -> every block does exactly 34 KV tiles. Wave w owns
// 32 q-rows. K/V double-buffered in LDS with counted vmcnt; Ps (XOR-swizzled)
// doubles as Q staging.

__global__ __launch_bounds__(256, 3) void attn(const bfu* __restrict__ Qg,
                                               const bfu* __restrict__ Kg,
                                               const bfu* __restrict__ Vtg,
                                               bfu* __restrict__ Ao) {
  __shared__ __align__(16) bfu Ks[2 * 64 * 64];
  __shared__ __align__(16) bfu Vs[2 * 64 * 64];
  __shared__ __align__(16) bfu Ps[128 * 64];  // also Q staging area (16KB)

  const int tid = threadIdx.x;
  const int lane = tid & 63;
  const int w = tid >> 6;
  const int l15 = lane & 15, l4 = lane >> 4;
  const int bh = blockIdx.y;
  const int b = bh >> 4, h = bh & 15;
  char* const PsB = (char*)Ps;

  for (int seg = 0; seg < 2; ++seg) {
    const int qb = (seg == 0) ? (int)blockIdx.x : 15 - (int)blockIdx.x;
    const int q0 = qb * 128;
    const int ntiles = 2 * qb + 2;
    const int wrow = q0 + w * 32;  // wave's first q row

    // ---- prologue: stage Q (into Ps) + KV tile 0 into buffer 0
#pragma unroll
    for (int i = 0; i < 4; ++i) {
      int lb = i * 256 + tid;
      int r = lb >> 3, c16 = (lb & 7) ^ (r & 7);
      gll16(Qg + ((size_t)bh * L_ + q0 + r) * DK_ + c16 * 8, PsB + (size_t)lb * 16);
    }
#pragma unroll
    for (int i = 0; i < 2; ++i) {
      int lb = i * 256 + tid;
      int r = lb >> 3, c16 = (lb & 7) ^ (r & 7);
      gll16(Kg + ((size_t)bh * L_ + r) * DK_ + c16 * 8, (char*)Ks + (size_t)lb * 16);
      gll16(Vtg + ((size_t)bh * DK_ + r) * L_ + c16 * 8, (char*)Vs + (size_t)lb * 16);
    }
    asm volatile("s_waitcnt vmcnt(0)" ::: "memory");
    asm volatile("s_barrier" ::: "memory");

    // ---- Q fragments (32 rows/wave)
    bf16x8 qf[2][2];
#pragma unroll
    for (int mi = 0; mi < 2; ++mi)
#pragma unroll
      for (int kk = 0; kk < 2; ++kk) {
        int r = w * 32 + mi * 16 + l15;
        int c16 = (kk * 4 + l4) ^ (r & 7);
        qf[mi][kk] = *(const bf16x8*)(PsB + (size_t)r * 128 + c16 * 16);
      }

    f32x4 acco[2][4] = {};
    float mst[2][4], lst[2][4];
#pragma unroll
    for (int mi = 0; mi < 2; ++mi)
#pragma unroll
      for (int rg = 0; rg < 4; ++rg) { mst[mi][rg] = -1e30f; lst[mi][rg] = 0.f; }

    for (int t = 0; t < ntiles; ++t) {
      const int cur = t & 1;
      const int kv0 = t * 64;
      const char* Kc = (const char*)Ks + cur * 8192;
      const char* Vc = (const char*)Vs + cur * 8192;

      if (t + 1 < ntiles) {
        const int nb = (t + 1) & 1;
        const int nkv = (t + 1) * 64;
#pragma unroll
        for (int i = 0; i < 2; ++i) {
          int lb = i * 256 + tid;
          int r = lb >> 3, c16 = (lb & 7) ^ (r & 7);
          gll16(Kg + ((size_t)bh * L_ + nkv + r) * DK_ + c16 * 8,
                (char*)Ks + nb * 8192 + (size_t)lb * 16);
          gll16(Vtg + ((size_t)bh * DK_ + r) * L_ + nkv + c16 * 8,
                (char*)Vs + nb * 8192 + (size_t)lb * 16);
        }
        asm volatile("s_waitcnt vmcnt(4) lgkmcnt(0)" ::: "memory");
      } else {
        asm volatile("s_waitcnt vmcnt(0) lgkmcnt(0)" ::: "memory");
      }
      asm volatile("s_barrier" ::: "memory");  // tile t staged for all waves

      if (kv0 <= wrow + 31) {  // wave has unmasked rows in this tile
        // ---- S = Q K^T (exp2 domain; Q pre-scaled by log2e/8)
        f32x4 s[2][4] = {};
#pragma unroll
        for (int kk = 0; kk < 2; ++kk)
#pragma unroll
          for (int ni = 0; ni < 4; ++ni) {
            int r = ni * 16 + l15;
            int c16 = (kk * 4 + l4) ^ (r & 7);
            bf16x8 kf = *(const bf16x8*)(Kc + (size_t)r * 128 + c16 * 16);
#pragma unroll
            for (int mi = 0; mi < 2; ++mi)
              s[mi][ni] = MFMA(qf[mi][kk], kf, s[mi][ni]);
          }

        if (t >= ntiles - 2) {  // diagonal band: mask kv > q
#pragma unroll
          for (int mi = 0; mi < 2; ++mi)
#pragma unroll
            for (int ni = 0; ni < 4; ++ni) {
              int kvg = kv0 + ni * 16 + l15;
#pragma unroll
              for (int rg = 0; rg < 4; ++rg) {
                int qg_ = wrow + mi * 16 + l4 * 4 + rg;
                if (kvg > qg_) s[mi][ni][rg] = -1e30f;
              }
            }
        }

        // ---- row maxes + defer-max
        float mx[2][4];
        float grow = -1.f;
#pragma unroll
        for (int mi = 0; mi < 2; ++mi)
#pragma unroll
          for (int rg = 0; rg < 4; ++rg) {
            float m0 = fmaxf(fmaxf(s[mi][0][rg], s[mi][1][rg]),
                             fmaxf(s[mi][2][rg], s[mi][3][rg]));
            m0 = fmaxf(m0, __shfl_xor(m0, 1));
            m0 = fmaxf(m0, __shfl_xor(m0, 2));
            m0 = fmaxf(m0, __shfl_xor(m0, 4));
            m0 = fmaxf(m0, __shfl_xor(m0, 8));
            mx[mi][rg] = m0;
            grow = fmaxf(grow, m0 - mst[mi][rg]);
          }
        if (__any(grow > 11.0f)) {  // rescale only when max grew materially
#pragma unroll
          for (int mi = 0; mi < 2; ++mi)
#pragma unroll
            for (int rg = 0; rg < 4; ++rg) {
              float mn = fmaxf(mst[mi][rg], mx[mi][rg]);
              float sc = __builtin_amdgcn_exp2f(mst[mi][rg] - mn);
              mst[mi][rg] = mn;
              lst[mi][rg] *= sc;
#pragma unroll
              for (int ni = 0; ni < 4; ++ni) acco[mi][ni][rg] *= sc;
            }
        }

        // ---- P = exp2(S - m), per-lane partial row sums, store to Ps (XOR swz)
#pragma unroll
        for (int mi = 0; mi < 2; ++mi)
#pragma unroll
          for (int ni = 0; ni < 4; ++ni) {
            int colB = (ni * 16 + l15) * 2;
#pragma unroll
            for (int rg = 0; rg < 4; ++rg) {
              float p = __builtin_amdgcn_exp2f(s[mi][ni][rg] - mst[mi][rg]);
              lst[mi][rg] += p;
              int row = w * 32 + mi * 16 + l4 * 4 + rg;
              *(bfu*)(PsB + row * 128 + (colB ^ ((row & 7) << 4))) = f2bf(p);
            }
          }

        // ---- O += P V
#pragma unroll
        for (int kk = 0; kk < 2; ++kk) {
          bf16x8 pf[2];
#pragma unroll
          for (int mi = 0; mi < 2; ++mi) {
            int row = w * 32 + mi * 16 + l15;
            pf[mi] = *(const bf16x8*)(PsB + row * 128 +
                                      ((kk * 64 + l4 * 16) ^ ((row & 7) << 4)));
          }
#pragma unroll
          for (int ni = 0; ni < 4; ++ni) {
            int r = ni * 16 + l15;
            int c16 = (kk * 4 + l4) ^ (r & 7);
            bf16x8 vf = *(const bf16x8*)(Vc + (size_t)r * 128 + c16 * 16);
#pragma unroll
            for (int mi = 0; mi < 2; ++mi)
              acco[mi][ni] = MFMA(pf[mi], vf, acco[mi][ni]);
          }
        }
      }  // active wave

      asm volatile("s_barrier" ::: "memory");  // all waves done with buf[cur]/Ps
    }

    // ---- epilogue: reduce row sums once, write O
#pragma unroll
    for (int mi = 0; mi < 2; ++mi)
#pragma unroll
      for (int rg = 0; rg < 4; ++rg) {
        float lsum = lst[mi][rg];
        lsum += __shfl_xor(lsum, 1);
        lsum += __shfl_xor(lsum, 2);
        lsum += __shfl_xor(lsum, 4);
        lsum += __shfl_xor(lsum, 8);
        float rinv = 1.0f / lsum;
        int lq = wrow + mi * 16 + l4 * 4 + rg;
#pragma unroll
        for (int ni = 0; ni < 4; ++ni) {
          int d = ni * 16 + l15;
          Ao[((size_t)b * L_ + lq) * D_ + h * DK_ + d] = f2bf(acco[mi][ni][rg] * rinv);
        }
      }
  }  // seg
}

// ---------------- launch ----------------

extern "C" void kernel_launch(void* const* d_in, const int* in_sizes, int n_in,
                              void* d_out, int out_size, void* d_ws, size_t ws_size,
                              hipStream_t stream) {
  const float* x = (const float*)d_in[0];
  const float* W_qkv = (const float*)d_in[1];
  const float* b_qkv = (const float*)d_in[2];
  const float* W_out = (const float*)d_in[3];
  const float* b_out = (const float*)d_in[4];
  float* out = (float*)d_out;

  char* ws = (char*)d_ws;
  bfu* xb     = (bfu*)(ws);                    // 8192*1024*2   = 16,777,216
  bfu* Wqkv_t = (bfu*)(ws + 16777216);         // 3072*1024*2   =  6,291,456
  bfu* Wout_t = (bfu*)(ws + 23068672);         // 1024*1024*2   =  2,097,152
  bfu* Qg     = (bfu*)(ws + 25165824);         // 16,777,216
  bfu* Kg     = (bfu*)(ws + 41943040);         // 16,777,216
  bfu* Vtg    = (bfu*)(ws + 58720256);         // 16,777,216
  bfu* Ao     = (bfu*)(ws + 75497472);         // 16,777,216  (total ~92.3 MB)

  cast_x<<<8192, 256, 0, stream>>>(x, xb, 2097152);
  transpose_cast<<<dim3(96, 32), dim3(32, 8), 0, stream>>>(W_qkv, Wqkv_t, 1024, 3072);
  transpose_cast<<<dim3(32, 32), dim3(32, 8), 0, stream>>>(W_out, Wout_t, 1024, 1024);

  gemm_bt<0><<<dim3(24, 64), 256, 0, stream>>>(xb, Wqkv_t, b_qkv, Qg, Kg, Vtg,
                                               nullptr, 8192, 3072, 1024);
  attn<<<dim3(8, 64), 256, 0, stream>>>(Qg, Kg, Vtg, Ao);
  gemm_bt<1><<<dim3(8, 64), 256, 0, stream>>>(Ao, Wout_t, b_out, nullptr, nullptr,
                                              nullptr, out, 8192, 1024, 1024);
}

// Round 3
// 201.630 us; speedup vs baseline: 1.7378x; 1.2554x over previous
//
#include <hip/hip_runtime.h>
#include <stdint.h>

#define B_ 4
#define L_ 2048
#define D_ 1024
#define H_ 16
#define DK_ 64

typedef __attribute__((ext_vector_type(8))) short bf16x8;
typedef __attribute__((ext_vector_type(4))) float f32x4;
typedef unsigned short bfu;   // raw bf16 storage

#define MFMA(a, b, c) __builtin_amdgcn_mfma_f32_16x16x32_bf16((a), (b), (c), 0, 0, 0)

__device__ __forceinline__ unsigned short f2bf(float f) {
  union { float f; unsigned int u; } v; v.f = f;
  unsigned int u = v.u;
  return (unsigned short)((u + 0x7fffu + ((u >> 16) & 1u)) >> 16);  // RNE
}

__device__ __forceinline__ void gll16(const void* g, void* l) {
  __builtin_amdgcn_global_load_lds(
      (const __attribute__((address_space(1))) void*)g,
      (__attribute__((address_space(3))) void*)l, 16, 0, 0);
}

__device__ __forceinline__ int bperm(int addr, int v) {
  return __builtin_amdgcn_ds_bpermute(addr, v);
}

// ---------------- prep kernels ----------------

__global__ __launch_bounds__(256) void cast_x(const float* __restrict__ in,
                                              bfu* __restrict__ out, int n4) {
  int i = blockIdx.x * 256 + threadIdx.x;
  if (i >= n4) return;
  float4 v = ((const float4*)in)[i];
  ushort4 o;
  o.x = f2bf(v.x); o.y = f2bf(v.y); o.z = f2bf(v.z); o.w = f2bf(v.w);
  ((ushort4*)out)[i] = o;
}

// in[R][C] fp32 -> out[C][R] bf16
__global__ void transpose_cast(const float* __restrict__ in, bfu* __restrict__ out,
                               int R, int C) {
  __shared__ float tile[32][33];
  int c0 = blockIdx.x * 32, r0 = blockIdx.y * 32;
  int tx = threadIdx.x, ty = threadIdx.y;  // 32 x 8
#pragma unroll
  for (int i = ty; i < 32; i += 8)
    tile[i][tx] = in[(size_t)(r0 + i) * C + c0 + tx];
  __syncthreads();
#pragma unroll
  for (int i = ty; i < 32; i += 8)
    out[(size_t)(c0 + i) * R + r0 + tx] = f2bf(tile[tx][i]);
}

// ---------------- BT GEMM: C[M][N] = A[M][K] * Bt[N][K]^T ----------------
// EPI 0: scatter to Q (scaled 1/8 * log2e), K ([B,H,L,DK]) and Vt ([B,H,DK,L])
// EPI 1: fp32 out[M][N] += bias

template <int EPI>
__global__ __launch_bounds__(256, 2) void gemm_bt(
    const bfu* __restrict__ A, const bfu* __restrict__ Bt,
    const float* __restrict__ bias, bfu* __restrict__ Qg, bfu* __restrict__ Kg,
    bfu* __restrict__ Vtg, float* __restrict__ Out, int M, int N, int K) {
  __shared__ __align__(16) bfu As[128 * 64];
  __shared__ __align__(16) bfu Bs[128 * 64];
  const int tid = threadIdx.x;
  const int lane = tid & 63;
  const int w = tid >> 6;
  const int wr = w >> 1, wc = w & 1;
  const int m0 = blockIdx.y * 128;
  const int n0 = blockIdx.x * 128;
  const int l15 = lane & 15, l4 = lane >> 4;

  f32x4 acc[4][4] = {};

  for (int k0 = 0; k0 < K; k0 += 64) {
    __syncthreads();
#pragma unroll
    for (int i = 0; i < 4; ++i) {
      int lb = i * 256 + tid;
      int r = lb >> 3;           // row in tile
      int c16p = lb & 7;         // physical 16B block in row
      int c16 = c16p ^ (r & 7);  // logical 16B block (pre-swizzled source)
      gll16(A + (size_t)(m0 + r) * K + k0 + c16 * 8, (char*)As + (size_t)lb * 16);
      gll16(Bt + (size_t)(n0 + r) * K + k0 + c16 * 8, (char*)Bs + (size_t)lb * 16);
    }
    __syncthreads();
#pragma unroll
    for (int kk = 0; kk < 2; ++kk) {
      bf16x8 af[4], bfr[4];
#pragma unroll
      for (int mi = 0; mi < 4; ++mi) {
        int r = wr * 64 + mi * 16 + l15;
        int c16 = (kk * 4 + l4) ^ (r & 7);
        af[mi] = *(const bf16x8*)((const char*)As + (size_t)r * 128 + c16 * 16);
      }
#pragma unroll
      for (int ni = 0; ni < 4; ++ni) {
        int r = wc * 64 + ni * 16 + l15;
        int c16 = (kk * 4 + l4) ^ (r & 7);
        bfr[ni] = *(const bf16x8*)((const char*)Bs + (size_t)r * 128 + c16 * 16);
      }
#pragma unroll
      for (int mi = 0; mi < 4; ++mi)
#pragma unroll
        for (int ni = 0; ni < 4; ++ni)
          acc[mi][ni] = MFMA(af[mi], bfr[ni], acc[mi][ni]);
    }
  }

  // epilogue: C/D layout col = lane&15, row = (lane>>4)*4 + reg
#pragma unroll
  for (int ni = 0; ni < 4; ++ni) {
    int gn = n0 + wc * 64 + ni * 16 + l15;
    float bv = bias[gn];
    if (EPI == 0) {
      int sec = gn >> 10;
      int rem = gn & 1023;
      int hh = rem >> 6, dk = rem & 63;
#pragma unroll
      for (int mi = 0; mi < 4; ++mi) {
#pragma unroll
        for (int rg = 0; rg < 4; ++rg) {
          int gm = m0 + wr * 64 + mi * 16 + l4 * 4 + rg;
          int bb = gm >> 11, ll = gm & 2047;
          float v = acc[mi][ni][rg] + bv;
          size_t hd = (size_t)(bb * H_ + hh);
          if (sec == 0)
            Qg[(hd * L_ + ll) * DK_ + dk] = f2bf(v * 0.18033688011112042f);  // (1/8)*log2(e)
          else if (sec == 1)
            Kg[(hd * L_ + ll) * DK_ + dk] = f2bf(v);
          else
            Vtg[(hd * DK_ + dk) * L_ + ll] = f2bf(v);
        }
      }
    } else {
#pragma unroll
      for (int mi = 0; mi < 4; ++mi)
#pragma unroll
        for (int rg = 0; rg < 4; ++rg) {
          int gm = m0 + wr * 64 + mi * 16 + l4 * 4 + rg;
          Out[(size_t)gm * 1024 + gn] = acc[mi][ni][rg] + bv;
        }
    }
  }
}

// ---------------- flash attention (causal), swapped-QK^T in-register softmax ----
// 1D grid 1024. XCD-bijective remap groups each bh's 16 q-blocks on one XCD.
// Block handles q-blocks {xq, 31-xq} of 64 rows (33 KV tiles total, perfect
// balance). 4 waves; wave w owns 16 q rows. S^T = mfma(K,Q) so each lane owns
// softmax stats of one q-row (q = lane&15). P goes to the PV A-fragment fully
// in-register via cvt_pk + ds_bpermute (no LDS round-trip).

__global__ __launch_bounds__(256, 4) void attn(const bfu* __restrict__ Qg,
                                               const bfu* __restrict__ Kg,
                                               const bfu* __restrict__ Vtg,
                                               bfu* __restrict__ Ao) {
  __shared__ __align__(16) bfu Ks[2 * 64 * 64];
  __shared__ __align__(16) bfu Vs[2 * 64 * 64];
  __shared__ __align__(16) bfu Qs[64 * 64];

  const int tid = threadIdx.x;
  const int lane = tid & 63;
  const int w = tid >> 6;
  const int l15 = lane & 15, l4 = lane >> 4;

  const int hid = blockIdx.x;
  const int xcd = hid & 7, slot = hid >> 3;
  const int bh = (xcd << 3) | (slot >> 4);   // 8 bh per XCD
  const int xq = slot & 15;
  const int b = bh >> 4, h = bh & 15;

  // bpermute byte-addrs for the P re-layout (4-lane group permutation)
  const int a0 = ((((l4 & 1) << 5) | l15) << 2);  // lane 2*(l4&1)*16 + l15
  const int a1 = a0 + 64;                          // +16 lanes

  for (int seg = 0; seg < 2; ++seg) {
    const int qb = (seg == 0) ? xq : 31 - xq;
    const int q0 = qb * 64;
    const int nt = qb + 1;

    // ---- prologue: stage Q + KV tile 0 (buffer 0)
#pragma unroll
    for (int i = 0; i < 2; ++i) {
      int lb = i * 256 + tid;
      int r = lb >> 3, c16 = (lb & 7) ^ (r & 7);
      gll16(Qg + ((size_t)bh * L_ + q0 + r) * DK_ + c16 * 8, (char*)Qs + lb * 16);
      gll16(Kg + ((size_t)bh * L_ + r) * DK_ + c16 * 8, (char*)Ks + lb * 16);
      gll16(Vtg + ((size_t)bh * DK_ + r) * L_ + c16 * 8, (char*)Vs + lb * 16);
    }
    asm volatile("s_waitcnt vmcnt(0)" ::: "memory");
    asm volatile("s_barrier" ::: "memory");

    // Q fragment (B-operand): Q[q = q0+w*16+l15][d = kk*32 + l4*8 ..+8)
    bf16x8 qf[2];
#pragma unroll
    for (int kk = 0; kk < 2; ++kk) {
      int r = w * 16 + l15;
      int c16 = (kk * 4 + l4) ^ (r & 7);
      qf[kk] = *(const bf16x8*)((const char*)Qs + r * 128 + c16 * 16);
    }

    f32x4 acco[4] = {};          // O[q = l4*4+rg (local)][d = ni*16+l15]
    float m = -1e30f, l = 0.f;   // per-lane: q = l15 (partial l across l4)

    for (int t = 0; t < nt; ++t) {
      const int cur = t & 1;
      const char* Kc = (const char*)Ks + cur * 8192;
      const char* Vc = (const char*)Vs + cur * 8192;

      if (t + 1 < nt) {
        const int nb = (t + 1) & 1, nkv = (t + 1) * 64;
#pragma unroll
        for (int i = 0; i < 2; ++i) {
          int lb = i * 256 + tid;
          int r = lb >> 3, c16 = (lb & 7) ^ (r & 7);
          gll16(Kg + ((size_t)bh * L_ + nkv + r) * DK_ + c16 * 8,
                (char*)Ks + nb * 8192 + lb * 16);
          gll16(Vtg + ((size_t)bh * DK_ + r) * L_ + nkv + c16 * 8,
                (char*)Vs + nb * 8192 + lb * 16);
        }
        asm volatile("s_waitcnt vmcnt(4)" ::: "memory");
      } else {
        asm volatile("s_waitcnt vmcnt(0)" ::: "memory");
      }
      asm volatile("s_barrier" ::: "memory");

      // ---- S^T = K Q^T : s[ni][rg] = S^T[kv = ni*16+l4*4+rg][q = l15]
      f32x4 s[4] = {};
      __builtin_amdgcn_s_setprio(1);
#pragma unroll
      for (int kk = 0; kk < 2; ++kk)
#pragma unroll
        for (int ni = 0; ni < 4; ++ni) {
          int r = ni * 16 + l15;
          int c16 = (kk * 4 + l4) ^ (r & 7);
          bf16x8 kf = *(const bf16x8*)(Kc + r * 128 + c16 * 16);
          s[ni] = MFMA(kf, qf[kk], s[ni]);
        }
      __builtin_amdgcn_s_setprio(0);

      if (t == nt - 1) {  // diagonal tile: mask kv > q (local indices)
        int ql = w * 16 + l15;
#pragma unroll
        for (int ni = 0; ni < 4; ++ni) {
          int kvl = ni * 16 + l4 * 4;
#pragma unroll
          for (int rg = 0; rg < 4; ++rg)
            if (kvl + rg > ql) s[ni][rg] = -1e30f;
        }
      }

      // ---- row max (in-lane 16 + cross-l4), defer-max rescale
      float mx = fmaxf(fmaxf(fmaxf(s[0][0], s[0][1]), fmaxf(s[0][2], s[0][3])),
                       fmaxf(fmaxf(s[1][0], s[1][1]), fmaxf(s[1][2], s[1][3])));
      mx = fmaxf(mx, fmaxf(fmaxf(fmaxf(s[2][0], s[2][1]), fmaxf(s[2][2], s[2][3])),
                           fmaxf(fmaxf(s[3][0], s[3][1]), fmaxf(s[3][2], s[3][3]))));
      mx = fmaxf(mx, __shfl_xor(mx, 16));
      mx = fmaxf(mx, __shfl_xor(mx, 32));
      if (__any(mx - m > 11.0f)) {
        float mn = fmaxf(m, mx);
        float sc = __builtin_amdgcn_exp2f(m - mn);
        m = mn;
        l *= sc;
#pragma unroll
        for (int rg = 0; rg < 4; ++rg) {
          float scq = __shfl(sc, l4 * 4 + rg);
          acco[0][rg] *= scq; acco[1][rg] *= scq;
          acco[2][rg] *= scq; acco[3][rg] *= scq;
        }
      }

      // ---- P = exp2(S^T - m), pack to bf16 pairs (kv ascending)
      uint32_t pk[4][2];
#pragma unroll
      for (int ni = 0; ni < 4; ++ni) {
        float p0 = __builtin_amdgcn_exp2f(s[ni][0] - m);
        float p1 = __builtin_amdgcn_exp2f(s[ni][1] - m);
        float p2 = __builtin_amdgcn_exp2f(s[ni][2] - m);
        float p3 = __builtin_amdgcn_exp2f(s[ni][3] - m);
        l += (p0 + p1) + (p2 + p3);
        asm("v_cvt_pk_bf16_f32 %0, %1, %2" : "=v"(pk[ni][0]) : "v"(p0), "v"(p1));
        asm("v_cvt_pk_bf16_f32 %0, %1, %2" : "=v"(pk[ni][1]) : "v"(p2), "v"(p3));
      }

      // ---- O += P V : A-frag P[q=l15][kv = kk*32 + l4*8 ..+8) via bpermute
      __builtin_amdgcn_s_setprio(1);
#pragma unroll
      for (int kk = 0; kk < 2; ++kk) {
        int za0 = bperm(a0, (int)pk[2 * kk][0]), zb0 = bperm(a0, (int)pk[2 * kk + 1][0]);
        int za1 = bperm(a0, (int)pk[2 * kk][1]), zb1 = bperm(a0, (int)pk[2 * kk + 1][1]);
        int za2 = bperm(a1, (int)pk[2 * kk][0]), zb2 = bperm(a1, (int)pk[2 * kk + 1][0]);
        int za3 = bperm(a1, (int)pk[2 * kk][1]), zb3 = bperm(a1, (int)pk[2 * kk + 1][1]);
        bool hi = (l4 >= 2);
        union { int wd[4]; bf16x8 v; } u;
        u.wd[0] = hi ? zb0 : za0;
        u.wd[1] = hi ? zb1 : za1;
        u.wd[2] = hi ? zb2 : za2;
        u.wd[3] = hi ? zb3 : za3;
#pragma unroll
        for (int ni = 0; ni < 4; ++ni) {
          int r = ni * 16 + l15;
          int c16 = (kk * 4 + l4) ^ (r & 7);
          bf16x8 vf = *(const bf16x8*)(Vc + r * 128 + c16 * 16);
          acco[ni] = MFMA(u.v, vf, acco[ni]);
        }
      }
      __builtin_amdgcn_s_setprio(0);

      asm volatile("s_barrier" ::: "memory");  // all waves done with buf[cur]
    }

    // ---- epilogue: reduce l across l4, redistribute to acco rows, write O
    float ls = l;
    ls += __shfl_xor(ls, 16);
    ls += __shfl_xor(ls, 32);
    float linv = 1.0f / ls;
#pragma unroll
    for (int rg = 0; rg < 4; ++rg) {
      float lq = __shfl(linv, l4 * 4 + rg);
      int q = q0 + w * 16 + l4 * 4 + rg;
#pragma unroll
      for (int ni = 0; ni < 4; ++ni) {
        int d = ni * 16 + l15;
        Ao[((size_t)b * L_ + q) * D_ + h * DK_ + d] = f2bf(acco[ni][rg] * lq);
      }
    }
  }  // seg
}

// ---------------- launch ----------------

extern "C" void kernel_launch(void* const* d_in, const int* in_sizes, int n_in,
                              void* d_out, int out_size, void* d_ws, size_t ws_size,
                              hipStream_t stream) {
  const float* x = (const float*)d_in[0];
  const float* W_qkv = (const float*)d_in[1];
  const float* b_qkv = (const float*)d_in[2];
  const float* W_out = (const float*)d_in[3];
  const float* b_out = (const float*)d_in[4];
  float* out = (float*)d_out;

  char* ws = (char*)d_ws;
  bfu* xb     = (bfu*)(ws);                    // 8192*1024*2   = 16,777,216
  bfu* Wqkv_t = (bfu*)(ws + 16777216);         // 3072*1024*2   =  6,291,456
  bfu* Wout_t = (bfu*)(ws + 23068672);         // 1024*1024*2   =  2,097,152
  bfu* Qg     = (bfu*)(ws + 25165824);         // 16,777,216
  bfu* Kg     = (bfu*)(ws + 41943040);         // 16,777,216
  bfu* Vtg    = (bfu*)(ws + 58720256);         // 16,777,216
  bfu* Ao     = (bfu*)(ws + 75497472);         // 16,777,216  (total ~92.3 MB)

  cast_x<<<8192, 256, 0, stream>>>(x, xb, 2097152);
  transpose_cast<<<dim3(96, 32), dim3(32, 8), 0, stream>>>(W_qkv, Wqkv_t, 1024, 3072);
  transpose_cast<<<dim3(32, 32), dim3(32, 8), 0, stream>>>(W_out, Wout_t, 1024, 1024);

  gemm_bt<0><<<dim3(24, 64), 256, 0, stream>>>(xb, Wqkv_t, b_qkv, Qg, Kg, Vtg,
                                               nullptr, 8192, 3072, 1024);
  attn<<<1024, 256, 0, stream>>>(Qg, Kg, Vtg, Ao);
  gemm_bt<1><<<dim3(8, 64), 256, 0, stream>>>(Ao, Wout_t, b_out, nullptr, nullptr,
                                              nullptr, out, 8192, 1024, 1024);
}

// Round 4
// 184.549 us; speedup vs baseline: 1.8986x; 1.0926x over previous
//
#include <hip/hip_runtime.h>
#include <stdint.h>

#define B_ 4
#define L_ 2048
#define D_ 1024
#define H_ 16
#define DK_ 64

typedef __attribute__((ext_vector_type(8))) short bf16x8;
typedef __attribute__((ext_vector_type(4))) float f32x4;
typedef unsigned short bfu;   // raw bf16 storage

#define MFMA(a, b, c) __builtin_amdgcn_mfma_f32_16x16x32_bf16((a), (b), (c), 0, 0, 0)

__device__ __forceinline__ unsigned short f2bf(float f) {
  union { float f; unsigned int u; } v; v.f = f;
  unsigned int u = v.u;
  return (unsigned short)((u + 0x7fffu + ((u >> 16) & 1u)) >> 16);  // RNE
}

__device__ __forceinline__ void gll16(const void* g, void* l) {
  __builtin_amdgcn_global_load_lds(
      (const __attribute__((address_space(1))) void*)g,
      (__attribute__((address_space(3))) void*)l, 16, 0, 0);
}

// ---------------- prep kernels ----------------

__global__ __launch_bounds__(256) void cast_x(const float* __restrict__ in,
                                              bfu* __restrict__ out, int n4) {
  int i = blockIdx.x * 256 + threadIdx.x;
  if (i >= n4) return;
  float4 v = ((const float4*)in)[i];
  ushort4 o;
  o.x = f2bf(v.x); o.y = f2bf(v.y); o.z = f2bf(v.z); o.w = f2bf(v.w);
  ((ushort4*)out)[i] = o;
}

// in[R][C] fp32 -> out[C][R] bf16
__global__ void transpose_cast(const float* __restrict__ in, bfu* __restrict__ out,
                               int R, int C) {
  __shared__ float tile[32][33];
  int c0 = blockIdx.x * 32, r0 = blockIdx.y * 32;
  int tx = threadIdx.x, ty = threadIdx.y;  // 32 x 8
#pragma unroll
  for (int i = ty; i < 32; i += 8)
    tile[i][tx] = in[(size_t)(r0 + i) * C + c0 + tx];
  __syncthreads();
#pragma unroll
  for (int i = ty; i < 32; i += 8)
    out[(size_t)(c0 + i) * R + r0 + tx] = f2bf(tile[tx][i]);
}

// ---------------- BT GEMM: C[M][N] = A[M][K] * Bt[N][K]^T ----------------
// EPI 0: scatter to Q (scaled 1/8 * log2(e)), K ([B,H,L,DK]) and Vt
//        ([B,H,DK,L] with kv-columns sigma^-1-permuted within 64-blocks so the
//        attn PV A-fragment needs no cross-lane relayout).
// EPI 1: fp32 out[M][N] += bias

template <int EPI>
__global__ __launch_bounds__(256, 3) void gemm_bt(
    const bfu* __restrict__ A, const bfu* __restrict__ Bt,
    const float* __restrict__ bias, bfu* __restrict__ Qg, bfu* __restrict__ Kg,
    bfu* __restrict__ Vtg, float* __restrict__ Out, int M, int N, int K) {
  __shared__ __align__(16) bfu As[128 * 64];
  __shared__ __align__(16) bfu Bs[128 * 64];
  const int tid = threadIdx.x;
  const int lane = tid & 63;
  const int w = tid >> 6;
  const int wr = w >> 1, wc = w & 1;
  const int m0 = blockIdx.y * 128;
  const int n0 = blockIdx.x * 128;
  const int l15 = lane & 15, l4 = lane >> 4;

  f32x4 acc[4][4] = {};

  for (int k0 = 0; k0 < K; k0 += 64) {
    __syncthreads();
#pragma unroll
    for (int i = 0; i < 4; ++i) {
      int lb = i * 256 + tid;
      int r = lb >> 3;           // row in tile
      int c16p = lb & 7;         // physical 16B block in row
      int c16 = c16p ^ (r & 7);  // logical 16B block (pre-swizzled source)
      gll16(A + (size_t)(m0 + r) * K + k0 + c16 * 8, (char*)As + (size_t)lb * 16);
      gll16(Bt + (size_t)(n0 + r) * K + k0 + c16 * 8, (char*)Bs + (size_t)lb * 16);
    }
    __syncthreads();
#pragma unroll
    for (int kk = 0; kk < 2; ++kk) {
      bf16x8 af[4], bfr[4];
#pragma unroll
      for (int mi = 0; mi < 4; ++mi) {
        int r = wr * 64 + mi * 16 + l15;
        int c16 = (kk * 4 + l4) ^ (r & 7);
        af[mi] = *(const bf16x8*)((const char*)As + (size_t)r * 128 + c16 * 16);
      }
#pragma unroll
      for (int ni = 0; ni < 4; ++ni) {
        int r = wc * 64 + ni * 16 + l15;
        int c16 = (kk * 4 + l4) ^ (r & 7);
        bfr[ni] = *(const bf16x8*)((const char*)Bs + (size_t)r * 128 + c16 * 16);
      }
#pragma unroll
      for (int mi = 0; mi < 4; ++mi)
#pragma unroll
        for (int ni = 0; ni < 4; ++ni)
          acc[mi][ni] = MFMA(af[mi], bfr[ni], acc[mi][ni]);
    }
  }

  // epilogue: C/D layout col = lane&15, row = (lane>>4)*4 + reg
#pragma unroll
  for (int ni = 0; ni < 4; ++ni) {
    int gn = n0 + wc * 64 + ni * 16 + l15;
    float bv = bias[gn];
    if (EPI == 0) {
      int sec = gn >> 10;
      int rem = gn & 1023;
      int hh = rem >> 6, dk = rem & 63;
#pragma unroll
      for (int mi = 0; mi < 4; ++mi) {
#pragma unroll
        for (int rg = 0; rg < 4; ++rg) {
          int gm = m0 + wr * 64 + mi * 16 + l4 * 4 + rg;
          int bb = gm >> 11, ll = gm & 2047;
          float v = acc[mi][ni][rg] + bv;
          size_t hd = (size_t)(bb * H_ + hh);
          if (sec == 0)
            Qg[(hd * L_ + ll) * DK_ + dk] = f2bf(v * 0.18033688011112042f);  // (1/8)*log2(e)
          else if (sec == 1)
            Kg[(hd * L_ + ll) * DK_ + dk] = f2bf(v);
          else {
            // sigma^-1 within the 64-aligned kv block:
            // s = (kv&32) | (((kv>>2)&3)<<3) | (((kv>>4)&1)<<2) | (kv&3)
            int kv = ll & 63;
            int s = (kv & 32) | (((kv >> 2) & 3) << 3) | (((kv >> 4) & 1) << 2) | (kv & 3);
            Vtg[(hd * DK_ + dk) * L_ + ((ll & ~63) | s)] = f2bf(v);
          }
        }
      }
    } else {
#pragma unroll
      for (int mi = 0; mi < 4; ++mi)
#pragma unroll
        for (int rg = 0; rg < 4; ++rg) {
          int gm = m0 + wr * 64 + mi * 16 + l4 * 4 + rg;
          Out[(size_t)gm * 1024 + gn] = acc[mi][ni][rg] + bv;
        }
    }
  }
}

// ---------------- flash attention (causal), swapped-QK^T in-register softmax ----
// 1D grid 1024. XCD-bijective remap groups each bh's 16 q-blocks on one XCD.
// Block handles q-blocks {xq, 31-xq} of 64 rows (33 KV tiles total, perfect
// balance). 4 waves; wave w owns 16 q rows. S^T = mfma(K,Q) so each lane owns
// softmax stats of one q-row (q = lane&15). Because V's kv-columns are stored
// sigma-permuted, the packed P words ARE the PV A-fragment — no cross-lane ops.

__global__ __launch_bounds__(256, 4) void attn(const bfu* __restrict__ Qg,
                                               const bfu* __restrict__ Kg,
                                               const bfu* __restrict__ Vtg,
                                               bfu* __restrict__ Ao) {
  __shared__ __align__(16) bfu Ks[2 * 64 * 64];
  __shared__ __align__(16) bfu Vs[2 * 64 * 64];
  __shared__ __align__(16) bfu Qs[64 * 64];

  const int tid = threadIdx.x;
  const int lane = tid & 63;
  const int w = tid >> 6;
  const int l15 = lane & 15, l4 = lane >> 4;

  const int hid = blockIdx.x;
  const int xcd = hid & 7, slot = hid >> 3;
  const int bh = (xcd << 3) | (slot >> 4);   // 8 bh per XCD
  const int xq = slot & 15;
  const int b = bh >> 4, h = bh & 15;

  for (int seg = 0; seg < 2; ++seg) {
    const int qb = (seg == 0) ? xq : 31 - xq;
    const int q0 = qb * 64;
    const int nt = qb + 1;

    // ---- prologue: stage Q + KV tile 0 (buffer 0)
#pragma unroll
    for (int i = 0; i < 2; ++i) {
      int lb = i * 256 + tid;
      int r = lb >> 3, c16 = (lb & 7) ^ (r & 7);
      gll16(Qg + ((size_t)bh * L_ + q0 + r) * DK_ + c16 * 8, (char*)Qs + lb * 16);
      gll16(Kg + ((size_t)bh * L_ + r) * DK_ + c16 * 8, (char*)Ks + lb * 16);
      gll16(Vtg + ((size_t)bh * DK_ + r) * L_ + c16 * 8, (char*)Vs + lb * 16);
    }
    asm volatile("s_waitcnt vmcnt(0)" ::: "memory");
    asm volatile("s_barrier" ::: "memory");

    // Q fragment (B-operand): Q[q = q0+w*16+l15][d = kk*32 + l4*8 ..+8)
    bf16x8 qf[2];
#pragma unroll
    for (int kk = 0; kk < 2; ++kk) {
      int r = w * 16 + l15;
      int c16 = (kk * 4 + l4) ^ (r & 7);
      qf[kk] = *(const bf16x8*)((const char*)Qs + r * 128 + c16 * 16);
    }

    f32x4 acco[4] = {};          // O[q = l4*4+rg (local)][d = ni*16+l15]
    float m = -1e30f, l = 0.f;   // per-lane: q = l15 (partial l across l4)

    for (int t = 0; t < nt; ++t) {
      const int cur = t & 1;
      const char* Kc = (const char*)Ks + cur * 8192;
      const char* Vc = (const char*)Vs + cur * 8192;

      if (t + 1 < nt) {
        const int nb = (t + 1) & 1, nkv = (t + 1) * 64;
#pragma unroll
        for (int i = 0; i < 2; ++i) {
          int lb = i * 256 + tid;
          int r = lb >> 3, c16 = (lb & 7) ^ (r & 7);
          gll16(Kg + ((size_t)bh * L_ + nkv + r) * DK_ + c16 * 8,
                (char*)Ks + nb * 8192 + lb * 16);
          gll16(Vtg + ((size_t)bh * DK_ + r) * L_ + nkv + c16 * 8,
                (char*)Vs + nb * 8192 + lb * 16);
        }
        asm volatile("s_waitcnt vmcnt(4)" ::: "memory");
      } else {
        asm volatile("s_waitcnt vmcnt(0)" ::: "memory");
      }
      asm volatile("s_barrier" ::: "memory");

      // ---- S^T = K Q^T : s[ni][rg] = S^T[kv = ni*16+l4*4+rg][q = l15]
      f32x4 s[4] = {};
      __builtin_amdgcn_s_setprio(1);
#pragma unroll
      for (int kk = 0; kk < 2; ++kk)
#pragma unroll
        for (int ni = 0; ni < 4; ++ni) {
          int r = ni * 16 + l15;
          int c16 = (kk * 4 + l4) ^ (r & 7);
          bf16x8 kf = *(const bf16x8*)(Kc + r * 128 + c16 * 16);
          s[ni] = MFMA(kf, qf[kk], s[ni]);
        }
      __builtin_amdgcn_s_setprio(0);

      if (t == nt - 1) {  // diagonal tile: mask kv > q (local indices)
        int ql = w * 16 + l15;
#pragma unroll
        for (int ni = 0; ni < 4; ++ni) {
          int kvl = ni * 16 + l4 * 4;
#pragma unroll
          for (int rg = 0; rg < 4; ++rg)
            if (kvl + rg > ql) s[ni][rg] = -1e30f;
        }
      }

      // ---- row max (in-lane 16 + cross-l4), defer-max rescale
      float mx = fmaxf(fmaxf(fmaxf(s[0][0], s[0][1]), fmaxf(s[0][2], s[0][3])),
                       fmaxf(fmaxf(s[1][0], s[1][1]), fmaxf(s[1][2], s[1][3])));
      mx = fmaxf(mx, fmaxf(fmaxf(fmaxf(s[2][0], s[2][1]), fmaxf(s[2][2], s[2][3])),
                           fmaxf(fmaxf(s[3][0], s[3][1]), fmaxf(s[3][2], s[3][3]))));
      mx = fmaxf(mx, __shfl_xor(mx, 16));
      mx = fmaxf(mx, __shfl_xor(mx, 32));
      if (__any(mx - m > 11.0f)) {
        float mn = fmaxf(m, mx);
        float sc = __builtin_amdgcn_exp2f(m - mn);
        m = mn;
        l *= sc;
#pragma unroll
        for (int rg = 0; rg < 4; ++rg) {
          float scq = __shfl(sc, l4 * 4 + rg);
          acco[0][rg] *= scq; acco[1][rg] *= scq;
          acco[2][rg] *= scq; acco[3][rg] *= scq;
        }
      }

      // ---- P = exp2(S^T - m), pack to bf16 pairs (kv ascending)
      uint32_t pk[4][2];
#pragma unroll
      for (int ni = 0; ni < 4; ++ni) {
        float p0 = __builtin_amdgcn_exp2f(s[ni][0] - m);
        float p1 = __builtin_amdgcn_exp2f(s[ni][1] - m);
        float p2 = __builtin_amdgcn_exp2f(s[ni][2] - m);
        float p3 = __builtin_amdgcn_exp2f(s[ni][3] - m);
        l += (p0 + p1) + (p2 + p3);
        asm("v_cvt_pk_bf16_f32 %0, %1, %2" : "=v"(pk[ni][0]) : "v"(p0), "v"(p1));
        asm("v_cvt_pk_bf16_f32 %0, %1, %2" : "=v"(pk[ni][1]) : "v"(p2), "v"(p3));
      }

      // ---- O += P V : pk words ARE the A-frag (V kv-columns pre-permuted)
      __builtin_amdgcn_s_setprio(1);
#pragma unroll
      for (int kk = 0; kk < 2; ++kk) {
        union { uint32_t wd[4]; bf16x8 v; } u;
        u.wd[0] = pk[2 * kk][0];
        u.wd[1] = pk[2 * kk][1];
        u.wd[2] = pk[2 * kk + 1][0];
        u.wd[3] = pk[2 * kk + 1][1];
#pragma unroll
        for (int ni = 0; ni < 4; ++ni) {
          int r = ni * 16 + l15;
          int c16 = (kk * 4 + l4) ^ (r & 7);
          bf16x8 vf = *(const bf16x8*)(Vc + r * 128 + c16 * 16);
          acco[ni] = MFMA(u.v, vf, acco[ni]);
        }
      }
      __builtin_amdgcn_s_setprio(0);

      asm volatile("s_barrier" ::: "memory");  // all waves done with buf[cur]
    }

    // ---- epilogue: reduce l across l4, redistribute to acco rows, write O
    float ls = l;
    ls += __shfl_xor(ls, 16);
    ls += __shfl_xor(ls, 32);
    float linv = 1.0f / ls;
#pragma unroll
    for (int rg = 0; rg < 4; ++rg) {
      float lq = __shfl(linv, l4 * 4 + rg);
      int q = q0 + w * 16 + l4 * 4 + rg;
#pragma unroll
      for (int ni = 0; ni < 4; ++ni) {
        int d = ni * 16 + l15;
        Ao[((size_t)b * L_ + q) * D_ + h * DK_ + d] = f2bf(acco[ni][rg] * lq);
      }
    }
  }  // seg
}

// ---------------- launch ----------------

extern "C" void kernel_launch(void* const* d_in, const int* in_sizes, int n_in,
                              void* d_out, int out_size, void* d_ws, size_t ws_size,
                              hipStream_t stream) {
  const float* x = (const float*)d_in[0];
  const float* W_qkv = (const float*)d_in[1];
  const float* b_qkv = (const float*)d_in[2];
  const float* W_out = (const float*)d_in[3];
  const float* b_out = (const float*)d_in[4];
  float* out = (float*)d_out;

  char* ws = (char*)d_ws;
  bfu* xb     = (bfu*)(ws);                    // 8192*1024*2   = 16,777,216
  bfu* Wqkv_t = (bfu*)(ws + 16777216);         // 3072*1024*2   =  6,291,456
  bfu* Wout_t = (bfu*)(ws + 23068672);         // 1024*1024*2   =  2,097,152
  bfu* Qg     = (bfu*)(ws + 25165824);         // 16,777,216
  bfu* Kg     = (bfu*)(ws + 41943040);         // 16,777,216
  bfu* Vtg    = (bfu*)(ws + 58720256);         // 16,777,216
  bfu* Ao     = (bfu*)(ws + 75497472);         // 16,777,216  (total ~92.3 MB)

  cast_x<<<8192, 256, 0, stream>>>(x, xb, 2097152);
  transpose_cast<<<dim3(96, 32), dim3(32, 8), 0, stream>>>(W_qkv, Wqkv_t, 1024, 3072);
  transpose_cast<<<dim3(32, 32), dim3(32, 8), 0, stream>>>(W_out, Wout_t, 1024, 1024);

  gemm_bt<0><<<dim3(24, 64), 256, 0, stream>>>(xb, Wqkv_t, b_qkv, Qg, Kg, Vtg,
                                               nullptr, 8192, 3072, 1024);
  attn<<<1024, 256, 0, stream>>>(Qg, Kg, Vtg, Ao);
  gemm_bt<1><<<dim3(8, 64), 256, 0, stream>>>(Ao, Wout_t, b_out, nullptr, nullptr,
                                              nullptr, out, 8192, 1024, 1024);
}

// Round 5
// 181.740 us; speedup vs baseline: 1.9280x; 1.0155x over previous
//
#include <hip/hip_runtime.h>
#include <stdint.h>

#define B_ 4
#define L_ 2048
#define D_ 1024
#define H_ 16
#define DK_ 64

typedef __attribute__((ext_vector_type(8))) short bf16x8;
typedef __attribute__((ext_vector_type(4))) float f32x4;
typedef unsigned short bfu;   // raw bf16 storage

#define MFMA(a, b, c) __builtin_amdgcn_mfma_f32_16x16x32_bf16((a), (b), (c), 0, 0, 0)

__device__ __forceinline__ unsigned short f2bf(float f) {
  union { float f; unsigned int u; } v; v.f = f;
  unsigned int u = v.u;
  return (unsigned short)((u + 0x7fffu + ((u >> 16) & 1u)) >> 16);  // RNE
}

__device__ __forceinline__ void gll16(const void* g, void* l) {
  __builtin_amdgcn_global_load_lds(
      (const __attribute__((address_space(1))) void*)g,
      (__attribute__((address_space(3))) void*)l, 16, 0, 0);
}

// ---------------- prep kernels ----------------

__global__ __launch_bounds__(256) void cast_x(const float* __restrict__ in,
                                              bfu* __restrict__ out, int n4) {
  int i = blockIdx.x * 256 + threadIdx.x;
  if (i >= n4) return;
  float4 v = ((const float4*)in)[i];
  ushort4 o;
  o.x = f2bf(v.x); o.y = f2bf(v.y); o.z = f2bf(v.z); o.w = f2bf(v.w);
  ((ushort4*)out)[i] = o;
}

// in[R][C] fp32 -> out[C][R] bf16
__global__ void transpose_cast(const float* __restrict__ in, bfu* __restrict__ out,
                               int R, int C) {
  __shared__ float tile[32][33];
  int c0 = blockIdx.x * 32, r0 = blockIdx.y * 32;
  int tx = threadIdx.x, ty = threadIdx.y;  // 32 x 8
#pragma unroll
  for (int i = ty; i < 32; i += 8)
    tile[i][tx] = in[(size_t)(r0 + i) * C + c0 + tx];
  __syncthreads();
#pragma unroll
  for (int i = ty; i < 32; i += 8)
    out[(size_t)(c0 + i) * R + r0 + tx] = f2bf(tile[tx][i]);
}

// ---------------- 256x256 8-phase BT GEMM ----------------
// C[M][N] = A[M][K] * Bt[N][K]^T. 512 threads = 8 waves (wm 2 x wn 4),
// per-wave output 128x64 (acc[8][4]). BK=64, double-buffered 128KB LDS,
// 4 phases/K-step, 1 half-tile stage/phase, counted vmcnt(4) (never 0 in
// the main loop). EPI 0: scatter Q (scaled log2e/8), K, and V (via LDS
// sigma^-1-permuted transpose -> [B,H,DK,L] contiguous writes).
// EPI 1: fp32 out[M][N] += bias.

template <int EPI>
__global__ __launch_bounds__(512, 2) void gemm8(
    const bfu* __restrict__ A, const bfu* __restrict__ Bt,
    const float* __restrict__ bias, bfu* __restrict__ Qg, bfu* __restrict__ Kg,
    bfu* __restrict__ Vtg, float* __restrict__ Out, int M, int N, int K) {
  __shared__ __align__(16) bfu LDSb[65536];  // 128 KB: A[2]@0, B[2]@32768
  const int tid = threadIdx.x;
  const int lane = tid & 63;
  const int w = tid >> 6;
  const int wm = w >> 2, wn = w & 3;
  const int l15 = lane & 15, l4 = lane >> 4;

  // XCD-bijective swizzle; m-fastest so consecutive swz share the B-panel
  const int nwg = gridDim.x;
  const int cpx = nwg >> 3;
  const int bid = (int)blockIdx.x;
  const int swz = (bid & 7) * cpx + (bid >> 3);
  const int m0 = (swz & 31) * 256;        // M = 8192 -> 32 m-tiles
  const int n0 = (swz >> 5) * 256;

  // stage one half-tile event ev of K-step t: 2 x gll16 per thread.
  // ev 0: A rows {0-63,128-191}   (read at phase 0)
  // ev 1: B rows {0-31,64-95,128-159,192-223} (phase 0)
  // ev 2: B rows ev1+32           (phase 1)
  // ev 3: A rows ev0+64           (phase 2)
#define STAGE(t_, ev_)                                                        \
  {                                                                           \
    const int c_ = (t_) & 1;                                                  \
    bfu* lb_ = ((ev_) == 0 || (ev_) == 3) ? (LDSb + c_ * 16384)               \
                                          : (LDSb + 32768 + c_ * 16384);      \
    const bfu* gs_ = ((ev_) == 0 || (ev_) == 3) ? A : Bt;                     \
    const int g0_ = ((ev_) == 0 || (ev_) == 3) ? m0 : n0;                     \
    _Pragma("unroll") for (int j_ = 0; j_ < 2; ++j_) {                        \
      int idx_ = j_ * 512 + tid;                                              \
      int r7_ = idx_ >> 3;                                                    \
      int row_;                                                               \
      if ((ev_) == 0) row_ = r7_ + ((r7_ >> 6) << 6);                         \
      else if ((ev_) == 3) row_ = 64 + r7_ + ((r7_ >> 6) << 6);               \
      else if ((ev_) == 1) row_ = r7_ + ((r7_ >> 5) << 5);                    \
      else row_ = 32 + r7_ + ((r7_ >> 5) << 5);                               \
      int c16_ = (idx_ & 7) ^ (row_ & 7);                                     \
      gll16(gs_ + (size_t)(g0_ + row_) * K + (t_) * 64 + c16_ * 8,            \
            (char*)lb_ + row_ * 128 + (idx_ & 7) * 16);                       \
    }                                                                         \
  }

#define VMCNT(n_) asm volatile("s_waitcnt vmcnt(" #n_ ")" ::: "memory")
#define BARRIER() asm volatile("s_barrier" ::: "memory")

  f32x4 acc[8][4] = {};
  bf16x8 af[4][2], bfA[2][2], bfB[2][2];

  auto lda = [&](int c, int half) {
    const char* base = (const char*)(LDSb + c * 16384);
#pragma unroll
    for (int mi = 0; mi < 4; ++mi)
#pragma unroll
      for (int kk = 0; kk < 2; ++kk) {
        int row = wm * 128 + half * 64 + mi * 16 + l15;
        int ch = (kk * 4 + l4) ^ (row & 7);
        af[mi][kk] = *(const bf16x8*)(base + row * 128 + ch * 16);
      }
  };
  auto ldb = [&](int c, int half, bf16x8 (*dst)[2]) {
    const char* base = (const char*)(LDSb + 32768 + c * 16384);
#pragma unroll
    for (int ni = 0; ni < 2; ++ni)
#pragma unroll
      for (int kk = 0; kk < 2; ++kk) {
        int row = wn * 64 + half * 32 + ni * 16 + l15;
        int ch = (kk * 4 + l4) ^ (row & 7);
        dst[ni][kk] = *(const bf16x8*)(base + row * 128 + ch * 16);
      }
  };

#define MM(mo_, no_, bfX_)                                                    \
  __builtin_amdgcn_s_setprio(1);                                              \
  _Pragma("unroll") for (int mi_ = 0; mi_ < 4; ++mi_)                         \
  _Pragma("unroll") for (int ni_ = 0; ni_ < 2; ++ni_)                         \
  _Pragma("unroll") for (int kk_ = 0; kk_ < 2; ++kk_)                         \
    acc[(mo_) + mi_][(no_) + ni_] =                                           \
        MFMA(af[mi_][kk_], bfX_[ni_][kk_], acc[(mo_) + mi_][(no_) + ni_]);    \
  __builtin_amdgcn_s_setprio(0);

  // ---- prologue: stage K-step 0 (events in order 0,1,2,3)
  STAGE(0, 0); STAGE(0, 1); STAGE(0, 2); STAGE(0, 3);
  VMCNT(4);   // A_lo(0), B_lo(0) landed
  BARRIER();

  const int NT = K >> 6;
  for (int t = 0; t < NT - 1; ++t) {
    const int c = t & 1, tn = t + 1;
    // phase 0: q0 = rows lo x cols 0-31
    lda(c, 0); ldb(c, 0, bfA);
    STAGE(tn, 0);
    MM(0, 0, bfA);
    VMCNT(4); BARRIER();   // guards p1's B_hi(t)
    // phase 1: q2 = rows lo x cols 32-63
    ldb(c, 1, bfB);
    STAGE(tn, 1);
    MM(0, 2, bfB);
    VMCNT(4); BARRIER();   // guards p2's A_hi(t)
    // phase 2: q3 = rows hi x cols 32-63
    lda(c, 1);
    STAGE(tn, 2);
    MM(4, 2, bfB);
    BARRIER();             // p3 reads nothing new
    // phase 3: q1 = rows hi x cols 0-31
    STAGE(tn, 3);
    MM(4, 0, bfA);
    VMCNT(4); BARRIER();   // guards next p0's A_lo/B_lo(t+1)
  }
  {  // peeled last K-step (no staging; drain)
    const int c = (NT - 1) & 1;
    lda(c, 0); ldb(c, 0, bfA);
    MM(0, 0, bfA);
    VMCNT(2); BARRIER();
    ldb(c, 1, bfB);
    MM(0, 2, bfB);
    VMCNT(0); BARRIER();
    lda(c, 1);
    MM(4, 2, bfB);
    MM(4, 0, bfA);
  }

  // ---- epilogue: C/D layout col = lane&15, row = (lane>>4)*4 + reg
  if (EPI == 1) {
#pragma unroll
    for (int ni = 0; ni < 4; ++ni) {
      int gn = n0 + wn * 64 + ni * 16 + l15;
      float bv = bias[gn];
#pragma unroll
      for (int mi = 0; mi < 8; ++mi)
#pragma unroll
        for (int rg = 0; rg < 4; ++rg) {
          int gm = m0 + wm * 128 + mi * 16 + l4 * 4 + rg;
          Out[(size_t)gm * N + gn] = acc[mi][ni][rg] + bv;
        }
    }
  } else {
    const int sec = n0 >> 10;  // 0..3 Q, 4..7 K, 8..11 V (256-wide n tiles)
    if (sec < 2) {
      bfu* dst = (sec == 0) ? Qg : Kg;
      const float scale = (sec == 0) ? 0.18033688011112042f : 1.0f;  // log2e/8
#pragma unroll
      for (int ni = 0; ni < 4; ++ni) {
        int gn = n0 + wn * 64 + ni * 16 + l15;
        int rem = gn & 1023;
        int hh = rem >> 6, dk = rem & 63;
        float bv = bias[gn];
#pragma unroll
        for (int mi = 0; mi < 8; ++mi)
#pragma unroll
          for (int rg = 0; rg < 4; ++rg) {
            int gm = m0 + wm * 128 + mi * 16 + l4 * 4 + rg;
            int bb = gm >> 11, ll = gm & 2047;
            dst[(((size_t)(bb * H_ + hh)) * L_ + ll) * DK_ + dk] =
                f2bf((acc[mi][ni][rg] + bv) * scale);
          }
      }
    } else {
      // V: transpose via LDS with sigma^-1 kv-permutation, contiguous stores
      __syncthreads();  // K-loop LDS reads done everywhere
#pragma unroll
      for (int ni = 0; ni < 4; ++ni) {
        int n_local = wn * 64 + ni * 16 + l15;
        int gn = n0 + n_local;
        float bv = bias[gn];
        int swzn = (n_local & 7) << 4;
#pragma unroll
        for (int mi = 0; mi < 8; ++mi) {
          int m_base = wm * 128 + mi * 16 + l4 * 4;
          int k6 = m_base & 63;
          int p0 = (m_base & ~63) |
                   ((k6 & 32) | (((k6 >> 2) & 3) << 3) | (((k6 >> 4) & 1) << 2));
          float v0 = acc[mi][ni][0] + bv, v1 = acc[mi][ni][1] + bv;
          float v2 = acc[mi][ni][2] + bv, v3 = acc[mi][ni][3] + bv;
          uint32_t w01, w23;
          asm("v_cvt_pk_bf16_f32 %0, %1, %2" : "=v"(w01) : "v"(v0), "v"(v1));
          asm("v_cvt_pk_bf16_f32 %0, %1, %2" : "=v"(w23) : "v"(v2), "v"(v3));
          *(uint32_t*)((char*)LDSb + n_local * 512 + ((2 * p0) ^ swzn)) = w01;
          *(uint32_t*)((char*)LDSb + n_local * 512 + ((2 * p0 + 4) ^ swzn)) = w23;
        }
      }
      __syncthreads();
      int n = tid >> 1;
      int cb = (tid & 1) * 16;
      int gnn = n0 + n;
      int hh = (gnn >> 6) & 15, dk = gnn & 63;
      size_t rowbase =
          (((size_t)((m0 >> 11) * H_ + hh)) * DK_ + dk) * L_ + (m0 & 2047);
#pragma unroll
      for (int j = 0; j < 16; ++j) {
        int ch = cb + j;
        bf16x8 vv = *(const bf16x8*)((char*)LDSb + n * 512 +
                                     ((ch * 16) ^ ((n & 7) << 4)));
        *(bf16x8*)(Vtg + rowbase + ch * 8) = vv;
      }
    }
  }
#undef STAGE
#undef VMCNT
#undef BARRIER
#undef MM
}

// ---------------- flash attention (causal), swapped-QK^T in-register softmax ----
// 1D grid 1024. XCD-bijective remap groups each bh's 16 q-blocks on one XCD.
// Block handles q-blocks {xq, 31-xq} of 64 rows (33 KV tiles total, perfect
// balance). 4 waves; wave w owns 16 q rows. S^T = mfma(K,Q) so each lane owns
// softmax stats of one q-row (q = lane&15). Because V's kv-columns are stored
// sigma-permuted, the packed P words ARE the PV A-fragment — no cross-lane ops.

__global__ __launch_bounds__(256, 4) void attn(const bfu* __restrict__ Qg,
                                               const bfu* __restrict__ Kg,
                                               const bfu* __restrict__ Vtg,
                                               bfu* __restrict__ Ao) {
  __shared__ __align__(16) bfu Ks[2 * 64 * 64];
  __shared__ __align__(16) bfu Vs[2 * 64 * 64];
  __shared__ __align__(16) bfu Qs[64 * 64];

  const int tid = threadIdx.x;
  const int lane = tid & 63;
  const int w = tid >> 6;
  const int l15 = lane & 15, l4 = lane >> 4;

  const int hid = blockIdx.x;
  const int xcd = hid & 7, slot = hid >> 3;
  const int bh = (xcd << 3) | (slot >> 4);   // 8 bh per XCD
  const int xq = slot & 15;
  const int b = bh >> 4, h = bh & 15;

  for (int seg = 0; seg < 2; ++seg) {
    const int qb = (seg == 0) ? xq : 31 - xq;
    const int q0 = qb * 64;
    const int nt = qb + 1;

    // ---- prologue: stage Q + KV tile 0 (buffer 0)
#pragma unroll
    for (int i = 0; i < 2; ++i) {
      int lb = i * 256 + tid;
      int r = lb >> 3, c16 = (lb & 7) ^ (r & 7);
      gll16(Qg + ((size_t)bh * L_ + q0 + r) * DK_ + c16 * 8, (char*)Qs + lb * 16);
      gll16(Kg + ((size_t)bh * L_ + r) * DK_ + c16 * 8, (char*)Ks + lb * 16);
      gll16(Vtg + ((size_t)bh * DK_ + r) * L_ + c16 * 8, (char*)Vs + lb * 16);
    }
    asm volatile("s_waitcnt vmcnt(0)" ::: "memory");
    asm volatile("s_barrier" ::: "memory");

    // Q fragment (B-operand): Q[q = q0+w*16+l15][d = kk*32 + l4*8 ..+8)
    bf16x8 qf[2];
#pragma unroll
    for (int kk = 0; kk < 2; ++kk) {
      int r = w * 16 + l15;
      int c16 = (kk * 4 + l4) ^ (r & 7);
      qf[kk] = *(const bf16x8*)((const char*)Qs + r * 128 + c16 * 16);
    }

    f32x4 acco[4] = {};          // O[q = l4*4+rg (local)][d = ni*16+l15]
    float m = -1e30f, l = 0.f;   // per-lane: q = l15 (partial l across l4)

    for (int t = 0; t < nt; ++t) {
      const int cur = t & 1;
      const char* Kc = (const char*)Ks + cur * 8192;
      const char* Vc = (const char*)Vs + cur * 8192;

      if (t + 1 < nt) {
        const int nb = (t + 1) & 1, nkv = (t + 1) * 64;
#pragma unroll
        for (int i = 0; i < 2; ++i) {
          int lb = i * 256 + tid;
          int r = lb >> 3, c16 = (lb & 7) ^ (r & 7);
          gll16(Kg + ((size_t)bh * L_ + nkv + r) * DK_ + c16 * 8,
                (char*)Ks + nb * 8192 + lb * 16);
          gll16(Vtg + ((size_t)bh * DK_ + r) * L_ + nkv + c16 * 8,
                (char*)Vs + nb * 8192 + lb * 16);
        }
        asm volatile("s_waitcnt vmcnt(4)" ::: "memory");
      } else {
        asm volatile("s_waitcnt vmcnt(0)" ::: "memory");
      }
      asm volatile("s_barrier" ::: "memory");

      // ---- S^T = K Q^T : s[ni][rg] = S^T[kv = ni*16+l4*4+rg][q = l15]
      f32x4 s[4] = {};
      __builtin_amdgcn_s_setprio(1);
#pragma unroll
      for (int kk = 0; kk < 2; ++kk)
#pragma unroll
        for (int ni = 0; ni < 4; ++ni) {
          int r = ni * 16 + l15;
          int c16 = (kk * 4 + l4) ^ (r & 7);
          bf16x8 kf = *(const bf16x8*)(Kc + r * 128 + c16 * 16);
          s[ni] = MFMA(kf, qf[kk], s[ni]);
        }
      __builtin_amdgcn_s_setprio(0);

      if (t == nt - 1) {  // diagonal tile: mask kv > q (local indices)
        int ql = w * 16 + l15;
#pragma unroll
        for (int ni = 0; ni < 4; ++ni) {
          int kvl = ni * 16 + l4 * 4;
#pragma unroll
          for (int rg = 0; rg < 4; ++rg)
            if (kvl + rg > ql) s[ni][rg] = -1e30f;
        }
      }

      // ---- row max (in-lane 16 + cross-l4), defer-max rescale
      float mx = fmaxf(fmaxf(fmaxf(s[0][0], s[0][1]), fmaxf(s[0][2], s[0][3])),
                       fmaxf(fmaxf(s[1][0], s[1][1]), fmaxf(s[1][2], s[1][3])));
      mx = fmaxf(mx, fmaxf(fmaxf(fmaxf(s[2][0], s[2][1]), fmaxf(s[2][2], s[2][3])),
                           fmaxf(fmaxf(s[3][0], s[3][1]), fmaxf(s[3][2], s[3][3]))));
      mx = fmaxf(mx, __shfl_xor(mx, 16));
      mx = fmaxf(mx, __shfl_xor(mx, 32));
      if (__any(mx - m > 11.0f)) {
        float mn = fmaxf(m, mx);
        float sc = __builtin_amdgcn_exp2f(m - mn);
        m = mn;
        l *= sc;
#pragma unroll
        for (int rg = 0; rg < 4; ++rg) {
          float scq = __shfl(sc, l4 * 4 + rg);
          acco[0][rg] *= scq; acco[1][rg] *= scq;
          acco[2][rg] *= scq; acco[3][rg] *= scq;
        }
      }

      // ---- P = exp2(S^T - m), pack to bf16 pairs (kv ascending)
      uint32_t pk[4][2];
#pragma unroll
      for (int ni = 0; ni < 4; ++ni) {
        float p0 = __builtin_amdgcn_exp2f(s[ni][0] - m);
        float p1 = __builtin_amdgcn_exp2f(s[ni][1] - m);
        float p2 = __builtin_amdgcn_exp2f(s[ni][2] - m);
        float p3 = __builtin_amdgcn_exp2f(s[ni][3] - m);
        l += (p0 + p1) + (p2 + p3);
        asm("v_cvt_pk_bf16_f32 %0, %1, %2" : "=v"(pk[ni][0]) : "v"(p0), "v"(p1));
        asm("v_cvt_pk_bf16_f32 %0, %1, %2" : "=v"(pk[ni][1]) : "v"(p2), "v"(p3));
      }

      // ---- O += P V : pk words ARE the A-frag (V kv-columns pre-permuted)
      __builtin_amdgcn_s_setprio(1);
#pragma unroll
      for (int kk = 0; kk < 2; ++kk) {
        union { uint32_t wd[4]; bf16x8 v; } u;
        u.wd[0] = pk[2 * kk][0];
        u.wd[1] = pk[2 * kk][1];
        u.wd[2] = pk[2 * kk + 1][0];
        u.wd[3] = pk[2 * kk + 1][1];
#pragma unroll
        for (int ni = 0; ni < 4; ++ni) {
          int r = ni * 16 + l15;
          int c16 = (kk * 4 + l4) ^ (r & 7);
          bf16x8 vf = *(const bf16x8*)(Vc + r * 128 + c16 * 16);
          acco[ni] = MFMA(u.v, vf, acco[ni]);
        }
      }
      __builtin_amdgcn_s_setprio(0);

      asm volatile("s_barrier" ::: "memory");  // all waves done with buf[cur]
    }

    // ---- epilogue: reduce l across l4, redistribute to acco rows, write O
    float ls = l;
    ls += __shfl_xor(ls, 16);
    ls += __shfl_xor(ls, 32);
    float linv = 1.0f / ls;
#pragma unroll
    for (int rg = 0; rg < 4; ++rg) {
      float lq = __shfl(linv, l4 * 4 + rg);
      int q = q0 + w * 16 + l4 * 4 + rg;
#pragma unroll
      for (int ni = 0; ni < 4; ++ni) {
        int d = ni * 16 + l15;
        Ao[((size_t)b * L_ + q) * D_ + h * DK_ + d] = f2bf(acco[ni][rg] * lq);
      }
    }
  }  // seg
}

// ---------------- launch ----------------

extern "C" void kernel_launch(void* const* d_in, const int* in_sizes, int n_in,
                              void* d_out, int out_size, void* d_ws, size_t ws_size,
                              hipStream_t stream) {
  const float* x = (const float*)d_in[0];
  const float* W_qkv = (const float*)d_in[1];
  const float* b_qkv = (const float*)d_in[2];
  const float* W_out = (const float*)d_in[3];
  const float* b_out = (const float*)d_in[4];
  float* out = (float*)d_out;

  char* ws = (char*)d_ws;
  bfu* xb     = (bfu*)(ws);                    // 8192*1024*2   = 16,777,216
  bfu* Wqkv_t = (bfu*)(ws + 16777216);         // 3072*1024*2   =  6,291,456
  bfu* Wout_t = (bfu*)(ws + 23068672);         // 1024*1024*2   =  2,097,152
  bfu* Qg     = (bfu*)(ws + 25165824);         // 16,777,216
  bfu* Kg     = (bfu*)(ws + 41943040);         // 16,777,216
  bfu* Vtg    = (bfu*)(ws + 58720256);         // 16,777,216
  bfu* Ao     = (bfu*)(ws + 75497472);         // 16,777,216  (total ~92.3 MB)

  cast_x<<<8192, 256, 0, stream>>>(x, xb, 2097152);
  transpose_cast<<<dim3(96, 32), dim3(32, 8), 0, stream>>>(W_qkv, Wqkv_t, 1024, 3072);
  transpose_cast<<<dim3(32, 32), dim3(32, 8), 0, stream>>>(W_out, Wout_t, 1024, 1024);

  gemm8<0><<<384, 512, 0, stream>>>(xb, Wqkv_t, b_qkv, Qg, Kg, Vtg, nullptr,
                                    8192, 3072, 1024);
  attn<<<1024, 256, 0, stream>>>(Qg, Kg, Vtg, Ao);
  gemm8<1><<<128, 512, 0, stream>>>(Ao, Wout_t, b_out, nullptr, nullptr, nullptr,
                                    out, 8192, 1024, 1024);
}